// Round 1
// baseline (1404.146 us; speedup 1.0000x reference)
//
#include <hip/hip_runtime.h>
#include <stdint.h>

#define CDIM 256
#define HW 2304
#define FR 3
#define NBATCH 2
#define NTOK 6912
#define EPSV 1e-6f
#define LOG2E 1.44269504088896f

typedef __attribute__((ext_vector_type(8))) short short8;
typedef __attribute__((ext_vector_type(4))) float f32x4;
typedef unsigned short u16;

__device__ inline u16 f2bf(float f) {
  union { float f; uint32_t u; } v; v.f = f;
  uint32_t r = v.u + 0x7FFFu + ((v.u >> 16) & 1u);
  return (u16)(r >> 16);
}

// ---------------- kernel 1: weights -> bf16 (scale folded into wq) ----------
__global__ void cvt_w_k(const float* wq, const float* wk, const float* wv,
                        const float* wp, u16* wb) {
  int idx = blockIdx.x * 256 + threadIdx.x;         // 0..65535
  wb[0 * 65536 + idx] = f2bf(wq[idx] * 0.0625f);    // fold c^-0.5 = 1/16
  wb[1 * 65536 + idx] = f2bf(wk[idx]);
  wb[2 * 65536 + idx] = f2bf(wv[idx]);
  wb[3 * 65536 + idx] = f2bf(wp[idx]);
}

// ---------------- kernel 2: GroupNorm stats per (b,g) -----------------------
__global__ void gn_stats_k(const float* x, float* stats) {
  int b = blockIdx.x >> 2, g = blockIdx.x & 3;
  int tid = threadIdx.x;
  float s1 = 0.f, s2 = 0.f;
  for (int i = tid; i < 64 * NTOK; i += 256) {
    int cl = i / NTOK; int rem = i - cl * NTOK;
    int f = rem / HW;  int hw = rem - f * HW;
    float v = x[((size_t)(f * NBATCH + b) * CDIM + g * 64 + cl) * HW + hw];
    s1 += v; s2 += v * v;
  }
  #pragma unroll
  for (int m = 32; m >= 1; m >>= 1) {
    s1 += __shfl_xor(s1, m, 64);
    s2 += __shfl_xor(s2, m, 64);
  }
  __shared__ float r1[4], r2[4];
  int wid = tid >> 6;
  if ((tid & 63) == 0) { r1[wid] = s1; r2[wid] = s2; }
  __syncthreads();
  if (tid == 0) {
    float t1 = r1[0] + r1[1] + r1[2] + r1[3];
    float t2 = r2[0] + r2[1] + r2[2] + r2[3];
    float inv = 1.f / (64.f * NTOK);
    float mu = t1 * inv;
    float var = t2 * inv - mu * mu;
    stats[blockIdx.x * 2 + 0] = mu;
    stats[blockIdx.x * 2 + 1] = rsqrtf(var + EPSV);
  }
}

// ---------------- kernel 3: normalize + transpose -> hn[b][n][c] bf16 -------
__global__ void gn_apply_k(const float* x, const float* gn_w, const float* gn_b,
                           const float* stats, u16* hn) {
  int nt = blockIdx.x, ct = blockIdx.y, b = blockIdx.z;
  int tid = threadIdx.x;
  __shared__ float tile[64][65];
  int n0 = nt * 64; int f = n0 / HW; int hw0 = n0 - f * HW;
  float mu = stats[(b * 4 + ct) * 2 + 0];
  float rs = stats[(b * 4 + ct) * 2 + 1];
  #pragma unroll
  for (int i = 0; i < 16; ++i) {
    int lin = i * 256 + tid;
    int cr = lin >> 6, nc = lin & 63;
    int c = ct * 64 + cr;
    float v = x[((size_t)(f * NBATCH + b) * CDIM + c) * HW + hw0 + nc];
    tile[cr][nc] = (v - mu) * rs * gn_w[c] + gn_b[c];
  }
  __syncthreads();
  #pragma unroll
  for (int i = 0; i < 16; ++i) {
    int lin = i * 256 + tid;
    int nr = lin >> 6, cc = lin & 63;
    hn[((size_t)b * NTOK + n0 + nr) * CDIM + ct * 64 + cc] = f2bf(tile[cc][nr]);
  }
}

// ---------------- kernel 4: QKV GEMM ----------------------------------------
// D[n][co] = sum_c hn[n][c] * w[co][c];  q,k -> [b][n][co], v -> [b][co][n]
__global__ __launch_bounds__(256) void qkv_k(const u16* hn, const u16* wb,
    const float* bq, const float* bk, const float* bv,
    u16* qb, u16* kb, u16* vb) {
  int nt = blockIdx.x;
  int op = blockIdx.y >> 1, b = blockIdx.y & 1;
  int tid = threadIdx.x, lane = tid & 63, wid = tid >> 6;
  int lr = lane & 15, lg = lane >> 4;
  __shared__ __align__(16) char hn_lds[32768];   // [64 n][256 c] swizzled
  __shared__ __align__(16) char w_lds[32768];    // [256 co][64 c] swizzled
  {
    const char* src = (const char*)(hn + ((size_t)b * NTOK + nt * 64) * CDIM);
    #pragma unroll
    for (int i = 0; i < 8; ++i) {
      int off = (i * 256 + tid) * 16;
      int row = off >> 9;
      short8 v = *(const short8*)(src + off);
      *(short8*)(hn_lds + (off ^ ((row & 7) << 4))) = v;
    }
  }
  f32x4 acc[16];
  #pragma unroll
  for (int i = 0; i < 16; ++i) acc[i] = (f32x4){0.f, 0.f, 0.f, 0.f};
  const u16* wsrc = wb + op * 65536;
  for (int cc = 0; cc < 4; ++cc) {
    if (cc) __syncthreads();
    #pragma unroll
    for (int i = 0; i < 8; ++i) {
      int off = (i * 256 + tid) * 16;
      int co = off >> 7; int colb = off & 127;
      short8 v = *(const short8*)(wsrc + (size_t)co * CDIM + cc * 64 + (colb >> 1));
      *(short8*)(w_lds + (off ^ ((co & 7) << 4))) = v;
    }
    __syncthreads();
    short8 afr[2];
    #pragma unroll
    for (int kc = 0; kc < 2; ++kc) {
      int row = wid * 16 + lr;
      int byte = row * 512 + (cc * 64 + kc * 32 + lg * 8) * 2;
      afr[kc] = *(const short8*)(hn_lds + (byte ^ ((row & 7) << 4)));
    }
    #pragma unroll
    for (int cot = 0; cot < 16; ++cot) {
      #pragma unroll
      for (int kc = 0; kc < 2; ++kc) {
        int co = cot * 16 + lr;
        int byte = co * 128 + (kc * 32 + lg * 8) * 2;
        short8 bfr = *(const short8*)(w_lds + (byte ^ ((co & 7) << 4)));
        acc[cot] = __builtin_amdgcn_mfma_f32_16x16x32_bf16(afr[kc], bfr, acc[cot], 0, 0, 0);
      }
    }
  }
  const float* bias = (op == 0) ? bq : (op == 1) ? bk : bv;
  float bscale = (op == 0) ? 0.0625f : 1.0f;
  int nbase = nt * 64 + wid * 16 + lg * 4;
  #pragma unroll
  for (int cot = 0; cot < 16; ++cot) {
    int co = cot * 16 + lr;
    float bv_ = bias[co] * bscale;
    #pragma unroll
    for (int j = 0; j < 4; ++j) {
      float val = acc[cot][j] + bv_;
      if (op == 2)
        vb[((size_t)b * CDIM + co) * NTOK + nbase + j] = f2bf(val);
      else {
        u16* dst = (op == 0) ? qb : kb;
        dst[((size_t)b * NTOK + nbase + j) * CDIM + co] = f2bf(val);
      }
    }
  }
}

// ---------------- kernel 5: flash attention ---------------------------------
// block: 64 queries, 4 waves x 16 rows; stream 108 KV tiles of 64
__global__ __launch_bounds__(256) void flash_k(const u16* qb, const u16* kb,
                                               const u16* vb, u16* ob) {
  int qt = blockIdx.x, b = blockIdx.y;
  int tid = threadIdx.x, lane = tid & 63, wid = tid >> 6;
  int lr = lane & 15, lg = lane >> 4;
  __shared__ __align__(16) char k_lds[32768];      // [64 m][256 c] swizzled
  __shared__ __align__(16) char v_lds[32768];      // [256 c][64 m] swizzled
  __shared__ __align__(16) char p_lds[4][2048];    // per-wave P [16 n][64 m]

  short8 aq[8];
  int nq = qt * 64 + wid * 16 + lr;
  const u16* qsrc = qb + ((size_t)b * NTOK + nq) * CDIM;
  #pragma unroll
  for (int kc = 0; kc < 8; ++kc) aq[kc] = *(const short8*)(qsrc + kc * 32 + lg * 8);

  float mrun[4], lrun[4];
  #pragma unroll
  for (int j = 0; j < 4; ++j) { mrun[j] = -1e30f; lrun[j] = 0.f; }
  f32x4 acc[16];
  #pragma unroll
  for (int i = 0; i < 16; ++i) acc[i] = (f32x4){0.f, 0.f, 0.f, 0.f};

  for (int kt = 0; kt < 108; ++kt) {
    {  // stage K tile (contiguous source)
      const char* src = (const char*)(kb + ((size_t)b * NTOK + kt * 64) * CDIM);
      #pragma unroll
      for (int i = 0; i < 8; ++i) {
        int off = (i * 256 + tid) * 16;
        int row = off >> 9;
        short8 v = *(const short8*)(src + off);
        *(short8*)(k_lds + (off ^ ((row & 7) << 4))) = v;
      }
      #pragma unroll
      for (int i = 0; i < 8; ++i) {  // stage V tile (strided rows of 128B)
        int off = (i * 256 + tid) * 16;
        int c = off >> 7; int colb = off & 127;
        short8 v = *(const short8*)(vb + ((size_t)b * CDIM + c) * NTOK + kt * 64 + (colb >> 1));
        *(short8*)(v_lds + (off ^ ((c & 7) << 4))) = v;
      }
    }
    __syncthreads();
    // S[n(16)][m(64)]: A=q rows, B=k rows
    f32x4 s[4];
    #pragma unroll
    for (int mt = 0; mt < 4; ++mt) {
      f32x4 a = (f32x4){0.f, 0.f, 0.f, 0.f};
      #pragma unroll
      for (int kc = 0; kc < 8; ++kc) {
        int row = mt * 16 + lr;
        int byte = row * 512 + (kc * 32 + lg * 8) * 2;
        short8 bfr = *(const short8*)(k_lds + (byte ^ ((row & 7) << 4)));
        a = __builtin_amdgcn_mfma_f32_16x16x32_bf16(aq[kc], bfr, a, 0, 0, 0);
      }
      s[mt] = a;
    }
    // online softmax; lane holds rows n = lg*4+j, cols m = mt*16+lr
    float rm[4], r[4];
    float pf[4][4];
    #pragma unroll
    for (int j = 0; j < 4; ++j)
      rm[j] = fmaxf(fmaxf(s[0][j], s[1][j]), fmaxf(s[2][j], s[3][j]));
    #pragma unroll
    for (int j = 0; j < 4; ++j) {
      #pragma unroll
      for (int m = 1; m <= 8; m <<= 1)
        rm[j] = fmaxf(rm[j], __shfl_xor(rm[j], m, 64));
    }
    #pragma unroll
    for (int j = 0; j < 4; ++j) {
      float mn = fmaxf(mrun[j], rm[j]);
      r[j] = exp2f((mrun[j] - mn) * LOG2E);
      mrun[j] = mn;
      float p0 = exp2f((s[0][j] - mn) * LOG2E);
      float p1 = exp2f((s[1][j] - mn) * LOG2E);
      float p2 = exp2f((s[2][j] - mn) * LOG2E);
      float p3 = exp2f((s[3][j] - mn) * LOG2E);
      pf[0][j] = p0; pf[1][j] = p1; pf[2][j] = p2; pf[3][j] = p3;
      float p = p0 + p1 + p2 + p3;
      #pragma unroll
      for (int m = 1; m <= 8; m <<= 1) p += __shfl_xor(p, m, 64);
      lrun[j] = lrun[j] * r[j] + p;
    }
    {  // rescale O accumulators (col n = lr needs r from group lr>>2, idx lr&3)
      int jj = lr & 3, gg = lr >> 2;
      float rg0 = __shfl(r[0], gg << 4, 64);
      float rg1 = __shfl(r[1], gg << 4, 64);
      float rg2 = __shfl(r[2], gg << 4, 64);
      float rg3 = __shfl(r[3], gg << 4, 64);
      float rn = (jj == 0) ? rg0 : (jj == 1) ? rg1 : (jj == 2) ? rg2 : rg3;
      #pragma unroll
      for (int i = 0; i < 16; ++i) {
        acc[i][0] *= rn; acc[i][1] *= rn; acc[i][2] *= rn; acc[i][3] *= rn;
      }
    }
    {  // write P[n][m] bf16 (per-wave, swizzled)
      char* pb = p_lds[wid];
      #pragma unroll
      for (int mt = 0; mt < 4; ++mt) {
        #pragma unroll
        for (int j = 0; j < 4; ++j) {
          int nn = lg * 4 + j;
          int byte = nn * 128 + mt * 32 + lr * 2;
          *(u16*)(pb + (byte ^ ((nn & 7) << 4))) = f2bf(pf[mt][j]);
        }
      }
    }
    // PV: O^T[c][n] += V^T[c][m] * P^T[m][n]
    #pragma unroll
    for (int mc = 0; mc < 2; ++mc) {
      int byteP = lr * 128 + (mc * 32 + lg * 8) * 2;
      short8 bfr = *(const short8*)(p_lds[wid] + (byteP ^ ((lr & 7) << 4)));
      #pragma unroll
      for (int ct = 0; ct < 16; ++ct) {
        int c = ct * 16 + lr;
        int byte = c * 128 + (mc * 32 + lg * 8) * 2;
        short8 av = *(const short8*)(v_lds + (byte ^ ((c & 7) << 4)));
        acc[ct] = __builtin_amdgcn_mfma_f32_16x16x32_bf16(av, bfr, acc[ct], 0, 0, 0);
      }
    }
    __syncthreads();
  }
  {  // epilogue: O /= l, write ob[b][n][c] bf16
    int jj = lr & 3, gg = lr >> 2;
    float li0 = 1.0f / lrun[0], li1 = 1.0f / lrun[1];
    float li2 = 1.0f / lrun[2], li3 = 1.0f / lrun[3];
    float lg0 = __shfl(li0, gg << 4, 64);
    float lg1 = __shfl(li1, gg << 4, 64);
    float lg2 = __shfl(li2, gg << 4, 64);
    float lg3 = __shfl(li3, gg << 4, 64);
    float linv = (jj == 0) ? lg0 : (jj == 1) ? lg1 : (jj == 2) ? lg2 : lg3;
    int n = qt * 64 + wid * 16 + lr;
    #pragma unroll
    for (int ct = 0; ct < 16; ++ct) {
      #pragma unroll
      for (int j = 0; j < 4; ++j) {
        int c = ct * 16 + lg * 4 + j;
        ob[((size_t)b * NTOK + n) * CDIM + c] = f2bf(acc[ct][j] * linv);
      }
    }
  }
}

// ---------------- kernel 6: proj_out + bias + residual ----------------------
// D[co][n] = sum_c wp[co][c] * o[n][c]; out[b*3+f][co][hw] = x[same] + D + bp
__global__ __launch_bounds__(256) void proj_k(const u16* ob, const u16* wb,
    const float* bp, const float* x, float* out) {
  int nt = blockIdx.x, b = blockIdx.y;
  int tid = threadIdx.x, lane = tid & 63, wid = tid >> 6;
  int lr = lane & 15, lg = lane >> 4;
  __shared__ __align__(16) char o_lds[32768];   // [64 n][256 c] swizzled
  const u16* wpb = wb + 3 * 65536;
  {
    const char* src = (const char*)(ob + ((size_t)b * NTOK + nt * 64) * CDIM);
    #pragma unroll
    for (int i = 0; i < 8; ++i) {
      int off = (i * 256 + tid) * 16;
      int row = off >> 9;
      short8 v = *(const short8*)(src + off);
      *(short8*)(o_lds + (off ^ ((row & 7) << 4))) = v;
    }
  }
  __syncthreads();
  #pragma unroll
  for (int ct2 = 0; ct2 < 4; ++ct2) {
    int cot = wid * 4 + ct2;
    short8 aw[8];
    #pragma unroll
    for (int kc = 0; kc < 8; ++kc)
      aw[kc] = *(const short8*)(wpb + (size_t)(cot * 16 + lr) * CDIM + kc * 32 + lg * 8);
    #pragma unroll
    for (int ntile = 0; ntile < 4; ++ntile) {
      f32x4 a = (f32x4){0.f, 0.f, 0.f, 0.f};
      #pragma unroll
      for (int kc = 0; kc < 8; ++kc) {
        int row = ntile * 16 + lr;
        int byte = row * 512 + (kc * 32 + lg * 8) * 2;
        short8 bfr = *(const short8*)(o_lds + (byte ^ ((row & 7) << 4)));
        a = __builtin_amdgcn_mfma_f32_16x16x32_bf16(aw[kc], bfr, a, 0, 0, 0);
      }
      int n = nt * 64 + ntile * 16 + lr;
      int f = n / HW; int hw = n - f * HW;
      #pragma unroll
      for (int j = 0; j < 4; ++j) {
        int co = cot * 16 + lg * 4 + j;
        float val = a[j] + bp[co];
        size_t oi = ((size_t)(b * FR + f) * CDIM + co) * HW + hw;
        out[oi] = x[oi] + val;
      }
    }
  }
}

extern "C" void kernel_launch(void* const* d_in, const int* in_sizes, int n_in,
                              void* d_out, int out_size, void* d_ws, size_t ws_size,
                              hipStream_t stream) {
  const float* x    = (const float*)d_in[0];
  const float* gn_w = (const float*)d_in[1];
  const float* gn_b = (const float*)d_in[2];
  const float* wq   = (const float*)d_in[3];
  const float* bq   = (const float*)d_in[4];
  const float* wk   = (const float*)d_in[5];
  const float* bk   = (const float*)d_in[6];
  const float* wv   = (const float*)d_in[7];
  const float* bv   = (const float*)d_in[8];
  const float* wp   = (const float*)d_in[9];
  const float* bp   = (const float*)d_in[10];
  float* out = (float*)d_out;
  char* ws = (char*)d_ws;

  float* stats = (float*)ws;                      // 16 f32
  u16* wb = (u16*)(ws + 256);                     // 4 x 256 x 256 bf16
  u16* hn = (u16*)(ws + 524544);                  // [2][6912][256]
  u16* qb = (u16*)(ws + 7602432);                 // [2][6912][256]
  u16* kb = (u16*)(ws + 14680320);                // [2][6912][256]
  u16* vb = (u16*)(ws + 21758208);                // [2][256][6912]
  u16* ob = (u16*)(ws + 28836096);                // [2][6912][256]

  cvt_w_k<<<256, 256, 0, stream>>>(wq, wk, wv, wp, wb);
  gn_stats_k<<<8, 256, 0, stream>>>(x, stats);
  gn_apply_k<<<dim3(108, 4, 2), 256, 0, stream>>>(x, gn_w, gn_b, stats, hn);
  qkv_k<<<dim3(108, 6), 256, 0, stream>>>(hn, wb, bq, bk, bv, qb, kb, vb);
  flash_k<<<dim3(108, 2), 256, 0, stream>>>(qb, kb, vb, ob);
  proj_k<<<dim3(108, 2), 256, 0, stream>>>(ob, wb, bp, x, out);
}

// Round 2
// 1108.679 us; speedup vs baseline: 1.2665x; 1.2665x over previous
//
#include <hip/hip_runtime.h>
#include <stdint.h>

#define CDIM 256
#define HW 2304
#define FR 3
#define NBATCH 2
#define NTOK 6912
#define NQT 108
#define EPSV 1e-6f
#define LOG2E 1.44269504088896f

typedef __attribute__((ext_vector_type(8))) short short8;
typedef __attribute__((ext_vector_type(4))) float f32x4;
typedef unsigned short u16;

__device__ inline u16 f2bf(float f) {
  union { float f; uint32_t u; } v; v.f = f;
  uint32_t r = v.u + 0x7FFFu + ((v.u >> 16) & 1u);
  return (u16)(r >> 16);
}
__device__ inline float bf2f(u16 h) {
  union { uint32_t u; float f; } v; v.u = ((uint32_t)h) << 16; return v.f;
}
// async global->LDS, 16B per lane; dest = wave-uniform base + lane*16
__device__ inline void gload16(const void* g, void* l) {
  __builtin_amdgcn_global_load_lds(
      (const __attribute__((address_space(1))) void*)g,
      (__attribute__((address_space(3))) void*)l, 16, 0, 0);
}

// ---------------- kernel 1: weights -> bf16 (scale folded into wq) ----------
__global__ void cvt_w_k(const float* wq, const float* wk, const float* wv,
                        const float* wp, u16* wb) {
  int idx = blockIdx.x * 256 + threadIdx.x;
  wb[0 * 65536 + idx] = f2bf(wq[idx] * 0.0625f);
  wb[1 * 65536 + idx] = f2bf(wk[idx]);
  wb[2 * 65536 + idx] = f2bf(wv[idx]);
  wb[3 * 65536 + idx] = f2bf(wp[idx]);
}

// ---------------- kernel 2a: GroupNorm partial sums (256 blocks) ------------
__global__ void gn_part_k(const float* x, float* part) {
  int bg = blockIdx.x >> 5, sl = blockIdx.x & 31;   // bg = b*4+g, 32 slices
  int b = bg >> 2, g = bg & 3;
  int tid = threadIdx.x;
  float s1 = 0.f, s2 = 0.f;
  for (int i = tid; i < 2 * NTOK; i += 256) {
    int cl = sl * 2 + (i / NTOK); int rem = i % NTOK;
    int f = rem / HW; int hw = rem - f * HW;
    float v = x[((size_t)(f * NBATCH + b) * CDIM + g * 64 + cl) * HW + hw];
    s1 += v; s2 += v * v;
  }
  #pragma unroll
  for (int m = 32; m >= 1; m >>= 1) {
    s1 += __shfl_xor(s1, m, 64);
    s2 += __shfl_xor(s2, m, 64);
  }
  __shared__ float r1[4], r2[4];
  int wid = tid >> 6;
  if ((tid & 63) == 0) { r1[wid] = s1; r2[wid] = s2; }
  __syncthreads();
  if (tid == 0) {
    part[blockIdx.x * 2 + 0] = r1[0] + r1[1] + r1[2] + r1[3];
    part[blockIdx.x * 2 + 1] = r2[0] + r2[1] + r2[2] + r2[3];
  }
}

// ---------------- kernel 2b: finalize stats ---------------------------------
__global__ void gn_fin_k(const float* part, float* stats) {
  int tid = threadIdx.x;
  if (tid < 8) {
    float s1 = 0.f, s2 = 0.f;
    for (int s = 0; s < 32; ++s) {
      s1 += part[(tid * 32 + s) * 2 + 0];
      s2 += part[(tid * 32 + s) * 2 + 1];
    }
    float inv = 1.f / (64.f * NTOK);
    float mu = s1 * inv;
    float var = s2 * inv - mu * mu;
    stats[tid * 2 + 0] = mu;
    stats[tid * 2 + 1] = rsqrtf(var + EPSV);
  }
}

// ---------------- kernel 3: normalize + transpose -> hn[b][n][c] bf16 -------
__global__ void gn_apply_k(const float* x, const float* gn_w, const float* gn_b,
                           const float* stats, u16* hn) {
  int nt = blockIdx.x, ct = blockIdx.y, b = blockIdx.z;
  int tid = threadIdx.x;
  __shared__ float tile[64][65];
  int n0 = nt * 64; int f = n0 / HW; int hw0 = n0 - f * HW;
  float mu = stats[(b * 4 + ct) * 2 + 0];
  float rs = stats[(b * 4 + ct) * 2 + 1];
  #pragma unroll
  for (int i = 0; i < 16; ++i) {
    int lin = i * 256 + tid;
    int cr = lin >> 6, nc = lin & 63;
    int c = ct * 64 + cr;
    float v = x[((size_t)(f * NBATCH + b) * CDIM + c) * HW + hw0 + nc];
    tile[cr][nc] = (v - mu) * rs * gn_w[c] + gn_b[c];
  }
  __syncthreads();
  #pragma unroll
  for (int i = 0; i < 16; ++i) {
    int lin = i * 256 + tid;
    int nr = lin >> 6, cc = lin & 63;
    hn[((size_t)b * NTOK + n0 + nr) * CDIM + ct * 64 + cc] = f2bf(tile[cc][nr]);
  }
}

// ---------------- kernel 4: QKV GEMM ----------------------------------------
// D[n][co] = sum_c hn[n][c] * w[co][c];  q,k -> [b][n][co], v -> [b][co][n]
// hn in LDS (gload_lds, swizzled); w fragments direct from global (L2-hot).
__global__ __launch_bounds__(256) void qkv_k(const u16* hn, const u16* wb,
    const float* bq, const float* bk, const float* bv,
    u16* qb, u16* kb, u16* vb) {
  int nt = blockIdx.x;
  int op = blockIdx.y >> 1, b = blockIdx.y & 1;
  int tid = threadIdx.x, lane = tid & 63, wid = tid >> 6;
  int lr = lane & 15, lg = lane >> 4;
  __shared__ __align__(16) char hn_lds[32768];   // [64 n][256 c] swizzled
  {
    const char* src = (const char*)(hn + ((size_t)b * NTOK + nt * 64) * CDIM);
    #pragma unroll
    for (int i = 0; i < 8; ++i) {
      int off = i * 4096 + wid * 1024 + lane * 16;
      int row = off >> 9;
      gload16(src + (off ^ ((row & 7) << 4)), hn_lds + i * 4096 + wid * 1024);
    }
  }
  __syncthreads();
  f32x4 acc[16];
  #pragma unroll
  for (int i = 0; i < 16; ++i) acc[i] = (f32x4){0.f, 0.f, 0.f, 0.f};
  const u16* wsrc = wb + op * 65536;
  __builtin_amdgcn_s_setprio(1);
  #pragma unroll
  for (int cc = 0; cc < 4; ++cc) {
    short8 afr[2];
    #pragma unroll
    for (int kc = 0; kc < 2; ++kc) {
      int row = wid * 16 + lr;
      int byte = row * 512 + (cc * 64 + kc * 32 + lg * 8) * 2;
      afr[kc] = *(const short8*)(hn_lds + (byte ^ ((row & 7) << 4)));
    }
    #pragma unroll
    for (int cot = 0; cot < 16; ++cot) {
      #pragma unroll
      for (int kc = 0; kc < 2; ++kc) {
        short8 bfr = *(const short8*)(wsrc + (size_t)(cot * 16 + lr) * CDIM +
                                      cc * 64 + kc * 32 + lg * 8);
        acc[cot] = __builtin_amdgcn_mfma_f32_16x16x32_bf16(afr[kc], bfr, acc[cot], 0, 0, 0);
      }
    }
  }
  __builtin_amdgcn_s_setprio(0);
  const float* bias = (op == 0) ? bq : (op == 1) ? bk : bv;
  float bscale = (op == 0) ? 0.0625f : 1.0f;
  int nbase = nt * 64 + wid * 16 + lg * 4;
  #pragma unroll
  for (int cot = 0; cot < 16; ++cot) {
    int co = cot * 16 + lr;
    float bv_ = bias[co] * bscale;
    #pragma unroll
    for (int j = 0; j < 4; ++j) {
      float val = acc[cot][j] + bv_;
      if (op == 2)
        vb[((size_t)b * CDIM + co) * NTOK + nbase + j] = f2bf(val);
      else {
        u16* dst = (op == 0) ? qb : kb;
        dst[((size_t)b * NTOK + nbase + j) * CDIM + co] = f2bf(val);
      }
    }
  }
}

// ---------------- kernel 5: flash attention (KV-split) ----------------------
// block: 64 queries, 4 waves x 16 rows; each block handles TPB KV tiles.
// K staged in LDS (gload_lds, swizzled); V fragments direct from global.
// DIRECT: single split -> normalized output. else: unnormalized partial + m,l.
template <int TPB, bool DIRECT>
__global__ __launch_bounds__(256) void flash_k(const u16* qb, const u16* kb,
                                               const u16* vb, u16* opart,
                                               float* ml, u16* ob) {
  constexpr int NSP = NQT / TPB;
  int qt = blockIdx.x, b = blockIdx.y, sp = blockIdx.z;
  int tid = threadIdx.x, lane = tid & 63, wid = tid >> 6;
  int lr = lane & 15, lg = lane >> 4;
  __shared__ __align__(16) char k_lds[32768];      // [64 m][256 c] swizzled
  __shared__ __align__(16) char p_lds[4][2048];    // per-wave P [16 n][64 m]

  short8 aq[8];
  int nq = qt * 64 + wid * 16 + lr;
  const u16* qsrc = qb + ((size_t)b * NTOK + nq) * CDIM;
  #pragma unroll
  for (int kc = 0; kc < 8; ++kc) aq[kc] = *(const short8*)(qsrc + kc * 32 + lg * 8);

  float mrun[4], lrun[4];
  #pragma unroll
  for (int j = 0; j < 4; ++j) { mrun[j] = -1e30f; lrun[j] = 0.f; }
  f32x4 acc[16];
  #pragma unroll
  for (int i = 0; i < 16; ++i) acc[i] = (f32x4){0.f, 0.f, 0.f, 0.f};

  const u16* vbase = vb + (size_t)b * CDIM * NTOK;

  for (int t = 0; t < TPB; ++t) {
    int kt = sp * TPB + t;
    {  // stage K tile: linear LDS dest, inverse-swizzled global source
      const char* src = (const char*)(kb + ((size_t)b * NTOK + kt * 64) * CDIM);
      #pragma unroll
      for (int i = 0; i < 8; ++i) {
        int off = i * 4096 + wid * 1024 + lane * 16;
        int row = off >> 9;
        gload16(src + (off ^ ((row & 7) << 4)), k_lds + i * 4096 + wid * 1024);
      }
    }
    __syncthreads();
    // S[n(16)][m(64)]: A=q rows, B=k rows
    f32x4 s[4];
    __builtin_amdgcn_s_setprio(1);
    #pragma unroll
    for (int mt = 0; mt < 4; ++mt) {
      f32x4 a = (f32x4){0.f, 0.f, 0.f, 0.f};
      #pragma unroll
      for (int kc = 0; kc < 8; ++kc) {
        int row = mt * 16 + lr;
        int byte = row * 512 + (kc * 32 + lg * 8) * 2;
        short8 bfr = *(const short8*)(k_lds + (byte ^ ((row & 7) << 4)));
        a = __builtin_amdgcn_mfma_f32_16x16x32_bf16(aq[kc], bfr, a, 0, 0, 0);
      }
      s[mt] = a;
    }
    __builtin_amdgcn_s_setprio(0);
    __syncthreads();   // k_lds fully consumed; next iter may restage
    // online softmax; lane holds rows n = lg*4+j, cols m = mt*16+lr
    float rm[4], r[4];
    float pf[4][4];
    #pragma unroll
    for (int j = 0; j < 4; ++j)
      rm[j] = fmaxf(fmaxf(s[0][j], s[1][j]), fmaxf(s[2][j], s[3][j]));
    #pragma unroll
    for (int j = 0; j < 4; ++j) {
      #pragma unroll
      for (int m = 1; m <= 8; m <<= 1)
        rm[j] = fmaxf(rm[j], __shfl_xor(rm[j], m, 64));
    }
    #pragma unroll
    for (int j = 0; j < 4; ++j) {
      float mn = fmaxf(mrun[j], rm[j]);
      r[j] = exp2f((mrun[j] - mn) * LOG2E);
      mrun[j] = mn;
      float p0 = exp2f((s[0][j] - mn) * LOG2E);
      float p1 = exp2f((s[1][j] - mn) * LOG2E);
      float p2 = exp2f((s[2][j] - mn) * LOG2E);
      float p3 = exp2f((s[3][j] - mn) * LOG2E);
      pf[0][j] = p0; pf[1][j] = p1; pf[2][j] = p2; pf[3][j] = p3;
      float p = p0 + p1 + p2 + p3;
      #pragma unroll
      for (int m = 1; m <= 8; m <<= 1) p += __shfl_xor(p, m, 64);
      lrun[j] = lrun[j] * r[j] + p;
    }
    {  // rescale O accumulators (cols are n = lr)
      int jj = lr & 3, gg = lr >> 2;
      float rg0 = __shfl(r[0], gg << 4, 64);
      float rg1 = __shfl(r[1], gg << 4, 64);
      float rg2 = __shfl(r[2], gg << 4, 64);
      float rg3 = __shfl(r[3], gg << 4, 64);
      float rn = (jj == 0) ? rg0 : (jj == 1) ? rg1 : (jj == 2) ? rg2 : rg3;
      #pragma unroll
      for (int i = 0; i < 16; ++i) {
        acc[i][0] *= rn; acc[i][1] *= rn; acc[i][2] *= rn; acc[i][3] *= rn;
      }
    }
    {  // write P[n][m] bf16 (per-wave, swizzled)
      char* pb = p_lds[wid];
      #pragma unroll
      for (int mt = 0; mt < 4; ++mt) {
        #pragma unroll
        for (int j = 0; j < 4; ++j) {
          int nn = lg * 4 + j;
          int byte = nn * 128 + mt * 32 + lr * 2;
          *(u16*)(pb + (byte ^ ((nn & 7) << 4))) = f2bf(pf[mt][j]);
        }
      }
    }
    // PV: O^T[c][n] += V^T[c][m] * P^T[m][n];  V fragments direct from global
    __builtin_amdgcn_s_setprio(1);
    #pragma unroll
    for (int mc = 0; mc < 2; ++mc) {
      int byteP = lr * 128 + (mc * 32 + lg * 8) * 2;
      short8 bfr = *(const short8*)(p_lds[wid] + (byteP ^ ((lr & 7) << 4)));
      #pragma unroll
      for (int ct = 0; ct < 16; ++ct) {
        short8 av = *(const short8*)(vbase + (size_t)(ct * 16 + lr) * NTOK +
                                     kt * 64 + mc * 32 + lg * 8);
        acc[ct] = __builtin_amdgcn_mfma_f32_16x16x32_bf16(av, bfr, acc[ct], 0, 0, 0);
      }
    }
    __builtin_amdgcn_s_setprio(0);
  }

  if (DIRECT) {  // normalize and write ob[b][n][c]
    int jj = lr & 3, gg = lr >> 2;
    float li0 = 1.0f / lrun[0], li1 = 1.0f / lrun[1];
    float li2 = 1.0f / lrun[2], li3 = 1.0f / lrun[3];
    float lg0 = __shfl(li0, gg << 4, 64);
    float lg1 = __shfl(li1, gg << 4, 64);
    float lg2 = __shfl(li2, gg << 4, 64);
    float lg3 = __shfl(li3, gg << 4, 64);
    float linv = (jj == 0) ? lg0 : (jj == 1) ? lg1 : (jj == 2) ? lg2 : lg3;
    int n = qt * 64 + wid * 16 + lr;
    #pragma unroll
    for (int ct = 0; ct < 16; ++ct) {
      #pragma unroll
      for (int j = 0; j < 4; ++j) {
        int c = ct * 16 + lg * 4 + j;
        ob[((size_t)b * NTOK + n) * CDIM + c] = f2bf(acc[ct][j] * linv);
      }
    }
  } else {  // unnormalized partial + m,l
    int base = (b * NQT + qt) * NSP + sp;
    #pragma unroll
    for (int ct = 0; ct < 16; ++ct) {
      #pragma unroll
      for (int j = 0; j < 4; ++j) {
        int c = ct * 16 + lg * 4 + j;
        opart[((size_t)base * 64 + wid * 16 + lr) * CDIM + c] = f2bf(acc[ct][j]);
      }
    }
    if (lr == 0) {
      #pragma unroll
      for (int j = 0; j < 4; ++j) {
        int row = wid * 16 + lg * 4 + j;
        ml[(size_t)base * 128 + row] = mrun[j];
        ml[(size_t)base * 128 + 64 + row] = lrun[j];
      }
    }
  }
}

// ---------------- kernel 5b: combine KV-split partials ----------------------
__global__ __launch_bounds__(256) void comb_k(const u16* opart, const float* ml,
                                              u16* ob) {
  int qt = blockIdx.x, b = blockIdx.y;
  int row = threadIdx.x >> 2;        // token within tile
  int cp = threadIdx.x & 3;          // 64-channel chunk
  int base = (b * NQT + qt) * 4;
  float m[4], l[4];
  #pragma unroll
  for (int s = 0; s < 4; ++s) {
    m[s] = ml[(size_t)(base + s) * 128 + row];
    l[s] = ml[(size_t)(base + s) * 128 + 64 + row];
  }
  float M = fmaxf(fmaxf(m[0], m[1]), fmaxf(m[2], m[3]));
  float w[4]; float den = 0.f;
  #pragma unroll
  for (int s = 0; s < 4; ++s) { w[s] = exp2f((m[s] - M) * LOG2E); den += w[s] * l[s]; }
  float inv = 1.f / den;
  int n = qt * 64 + row;
  #pragma unroll
  for (int cc = 0; cc < 8; ++cc) {
    int c0 = cp * 64 + cc * 8;
    float o[8] = {0.f, 0.f, 0.f, 0.f, 0.f, 0.f, 0.f, 0.f};
    #pragma unroll
    for (int s = 0; s < 4; ++s) {
      short8 v = *(const short8*)(opart + ((size_t)(base + s) * 64 + row) * CDIM + c0);
      #pragma unroll
      for (int j = 0; j < 8; ++j) o[j] += w[s] * bf2f((u16)v[j]);
    }
    short8 r8;
    #pragma unroll
    for (int j = 0; j < 8; ++j) r8[j] = (short)f2bf(o[j] * inv);
    *(short8*)(ob + ((size_t)b * NTOK + n) * CDIM + c0) = r8;
  }
}

// ---------------- kernel 6: proj_out + bias + residual ----------------------
// D[co][n] = sum_c wp[co][c] * o[n][c]; out[b*3+f][co][hw] = x[same] + D + bp
// co-split over blockIdx.z for grid size.
__global__ __launch_bounds__(256) void proj_k(const u16* ob, const u16* wb,
    const float* bp, const float* x, float* out) {
  int nt = blockIdx.x, b = blockIdx.y, z = blockIdx.z;
  int tid = threadIdx.x, lane = tid & 63, wid = tid >> 6;
  int lr = lane & 15, lg = lane >> 4;
  __shared__ __align__(16) char o_lds[32768];   // [64 n][256 c] swizzled
  const u16* wpb = wb + 3 * 65536;
  {
    const char* src = (const char*)(ob + ((size_t)b * NTOK + nt * 64) * CDIM);
    #pragma unroll
    for (int i = 0; i < 8; ++i) {
      int off = i * 4096 + wid * 1024 + lane * 16;
      int row = off >> 9;
      gload16(src + (off ^ ((row & 7) << 4)), o_lds + i * 4096 + wid * 1024);
    }
  }
  __syncthreads();
  #pragma unroll
  for (int ct2 = 0; ct2 < 2; ++ct2) {
    int cot = z * 8 + wid * 2 + ct2;
    short8 aw[8];
    #pragma unroll
    for (int kc = 0; kc < 8; ++kc)
      aw[kc] = *(const short8*)(wpb + (size_t)(cot * 16 + lr) * CDIM + kc * 32 + lg * 8);
    #pragma unroll
    for (int ntile = 0; ntile < 4; ++ntile) {
      f32x4 a = (f32x4){0.f, 0.f, 0.f, 0.f};
      #pragma unroll
      for (int kc = 0; kc < 8; ++kc) {
        int row = ntile * 16 + lr;
        int byte = row * 512 + (kc * 32 + lg * 8) * 2;
        short8 bfr = *(const short8*)(o_lds + (byte ^ ((row & 7) << 4)));
        a = __builtin_amdgcn_mfma_f32_16x16x32_bf16(aw[kc], bfr, a, 0, 0, 0);
      }
      int n = nt * 64 + ntile * 16 + lr;
      int f = n / HW; int hw = n - f * HW;
      #pragma unroll
      for (int j = 0; j < 4; ++j) {
        int co = cot * 16 + lg * 4 + j;
        float val = a[j] + bp[co];
        size_t oi = ((size_t)(b * FR + f) * CDIM + co) * HW + hw;
        out[oi] = x[oi] + val;
      }
    }
  }
}

extern "C" void kernel_launch(void* const* d_in, const int* in_sizes, int n_in,
                              void* d_out, int out_size, void* d_ws, size_t ws_size,
                              hipStream_t stream) {
  const float* x    = (const float*)d_in[0];
  const float* gn_w = (const float*)d_in[1];
  const float* gn_b = (const float*)d_in[2];
  const float* wq   = (const float*)d_in[3];
  const float* bq   = (const float*)d_in[4];
  const float* wk   = (const float*)d_in[5];
  const float* bk   = (const float*)d_in[6];
  const float* wv   = (const float*)d_in[7];
  const float* bv   = (const float*)d_in[8];
  const float* wp   = (const float*)d_in[9];
  const float* bp   = (const float*)d_in[10];
  float* out = (float*)d_out;
  char* ws = (char*)d_ws;

  float* stats = (float*)(ws + 0);          // 16 f32
  float* part  = (float*)(ws + 256);        // 256*2 f32
  u16* wb = (u16*)(ws + 4096);              // 4*256*256
  u16* hn = (u16*)(ws + 528384);            // [2][6912][256]
  u16* qb = (u16*)(ws + 7606272);
  u16* kb = (u16*)(ws + 14684160);
  u16* vb = (u16*)(ws + 21762048);          // [2][256][6912]
  u16* ob = (u16*)(ws + 28839936);
  u16* opart = (u16*)(ws + 35917824);       // [2*108*4][64][256] bf16
  float* ml  = (float*)(ws + 64229376);     // [2*108*4][128] f32
  const size_t NEED_SPLIT = 64671744;

  cvt_w_k<<<256, 256, 0, stream>>>(wq, wk, wv, wp, wb);
  gn_part_k<<<256, 256, 0, stream>>>(x, part);
  gn_fin_k<<<1, 64, 0, stream>>>(part, stats);
  gn_apply_k<<<dim3(108, 4, 2), 256, 0, stream>>>(x, gn_w, gn_b, stats, hn);
  qkv_k<<<dim3(108, 6), 256, 0, stream>>>(hn, wb, bq, bk, bv, qb, kb, vb);
  if (ws_size >= NEED_SPLIT) {
    flash_k<27, false><<<dim3(108, 2, 4), 256, 0, stream>>>(qb, kb, vb, opart, ml, ob);
    comb_k<<<dim3(108, 2), 256, 0, stream>>>(opart, ml, ob);
  } else {
    flash_k<108, true><<<dim3(108, 2, 1), 256, 0, stream>>>(qb, kb, vb, opart, ml, ob);
  }
  proj_k<<<dim3(108, 2, 2), 256, 0, stream>>>(ob, wb, bp, x, out);
}

// Round 3
// 589.351 us; speedup vs baseline: 2.3825x; 1.8812x over previous
//
#include <hip/hip_runtime.h>
#include <stdint.h>

#define CDIM 256
#define HW 2304
#define FR 3
#define NBATCH 2
#define NTOK 6912
#define EPSV 1e-6f
#define LOG2E 1.44269504088896f
#define QSCALE (0.0625f * 1.44269504088896f)

typedef __attribute__((ext_vector_type(8))) short short8;
typedef __attribute__((ext_vector_type(4))) float f32x4;
typedef unsigned short u16;

__device__ inline u16 f2bf(float f) {
  union { float f; uint32_t u; } v; v.f = f;
  uint32_t r = v.u + 0x7FFFu + ((v.u >> 16) & 1u);
  return (u16)(r >> 16);
}
__device__ inline float bf2f(u16 h) {
  union { uint32_t u; float f; } v; v.u = ((uint32_t)h) << 16; return v.f;
}
// async global->LDS, 16B per lane; dest = wave-uniform base + lane*16
__device__ inline void gload16(const void* g, void* l) {
  __builtin_amdgcn_global_load_lds(
      (const __attribute__((address_space(1))) void*)g,
      (__attribute__((address_space(3))) void*)l, 16, 0, 0);
}

// ---------------- kernel 1: weights -> bf16 (scale+LOG2E folded into wq) ----
__global__ void cvt_w_k(const float* wq, const float* wk, const float* wv,
                        const float* wp, u16* wb) {
  int idx = blockIdx.x * 256 + threadIdx.x;
  wb[0 * 65536 + idx] = f2bf(wq[idx] * QSCALE);
  wb[1 * 65536 + idx] = f2bf(wk[idx]);
  wb[2 * 65536 + idx] = f2bf(wv[idx]);
  wb[3 * 65536 + idx] = f2bf(wp[idx]);
}

// ---------------- kernel 2a: GroupNorm partial sums (256 blocks) ------------
__global__ void gn_part_k(const float* x, float* part) {
  int bg = blockIdx.x >> 5, sl = blockIdx.x & 31;
  int b = bg >> 2, g = bg & 3;
  int tid = threadIdx.x;
  float s1 = 0.f, s2 = 0.f;
  for (int i = tid; i < 2 * NTOK; i += 256) {
    int cl = sl * 2 + (i / NTOK); int rem = i % NTOK;
    int f = rem / HW; int hw = rem - f * HW;
    float v = x[((size_t)(f * NBATCH + b) * CDIM + g * 64 + cl) * HW + hw];
    s1 += v; s2 += v * v;
  }
  #pragma unroll
  for (int m = 32; m >= 1; m >>= 1) {
    s1 += __shfl_xor(s1, m, 64);
    s2 += __shfl_xor(s2, m, 64);
  }
  __shared__ float r1[4], r2[4];
  int wid = tid >> 6;
  if ((tid & 63) == 0) { r1[wid] = s1; r2[wid] = s2; }
  __syncthreads();
  if (tid == 0) {
    part[blockIdx.x * 2 + 0] = r1[0] + r1[1] + r1[2] + r1[3];
    part[blockIdx.x * 2 + 1] = r2[0] + r2[1] + r2[2] + r2[3];
  }
}

// ---------------- kernel 2b: finalize stats ---------------------------------
__global__ void gn_fin_k(const float* part, float* stats) {
  int tid = threadIdx.x;
  if (tid < 8) {
    float s1 = 0.f, s2 = 0.f;
    for (int s = 0; s < 32; ++s) {
      s1 += part[(tid * 32 + s) * 2 + 0];
      s2 += part[(tid * 32 + s) * 2 + 1];
    }
    float inv = 1.f / (64.f * NTOK);
    float mu = s1 * inv;
    float var = s2 * inv - mu * mu;
    stats[tid * 2 + 0] = mu;
    stats[tid * 2 + 1] = rsqrtf(var + EPSV);
  }
}

// ---------------- kernel 3: normalize + transpose -> hn[b][n][c] bf16 -------
__global__ void gn_apply_k(const float* x, const float* gn_w, const float* gn_b,
                           const float* stats, u16* hn) {
  int nt = blockIdx.x, ct = blockIdx.y, b = blockIdx.z;
  int tid = threadIdx.x;
  __shared__ float tile[64][65];
  int n0 = nt * 64; int f = n0 / HW; int hw0 = n0 - f * HW;
  float mu = stats[(b * 4 + ct) * 2 + 0];
  float rs = stats[(b * 4 + ct) * 2 + 1];
  #pragma unroll
  for (int i = 0; i < 16; ++i) {
    int lin = i * 256 + tid;
    int cr = lin >> 6, nc = lin & 63;
    int c = ct * 64 + cr;
    float v = x[((size_t)(f * NBATCH + b) * CDIM + c) * HW + hw0 + nc];
    tile[cr][nc] = (v - mu) * rs * gn_w[c] + gn_b[c];
  }
  __syncthreads();
  #pragma unroll
  for (int i = 0; i < 16; ++i) {
    int lin = i * 256 + tid;
    int nr = lin >> 6, cc = lin & 63;
    hn[((size_t)b * NTOK + n0 + nr) * CDIM + ct * 64 + cc] = f2bf(tile[cc][nr]);
  }
}

// ---------------- kernel 4: QKV GEMM ----------------------------------------
// D[n][co] = sum_c hn[n][c] * w[co][c]
// q -> [b][n][co] (scaled, log2-domain); v -> [b][co][n]
// k -> rotated tile layout: kb[b][tile][row][slot][8] with slot=((co>>3)+2*row)&31
__global__ __launch_bounds__(256) void qkv_k(const u16* hn, const u16* wb,
    const float* bq, const float* bk, const float* bv,
    u16* qb, u16* kb, u16* vb) {
  int nt = blockIdx.x;
  int op = blockIdx.y >> 1, b = blockIdx.y & 1;
  int tid = threadIdx.x, lane = tid & 63, wid = tid >> 6;
  int lr = lane & 15, lg = lane >> 4;
  __shared__ __align__(16) char hn_lds[32768];   // [64 n][256 c] swizzled
  {
    const char* src = (const char*)(hn + ((size_t)b * NTOK + nt * 64) * CDIM);
    #pragma unroll
    for (int i = 0; i < 8; ++i) {
      int off = i * 4096 + wid * 1024 + lane * 16;
      int row = off >> 9;
      gload16(src + (off ^ ((row & 7) << 4)), hn_lds + i * 4096 + wid * 1024);
    }
  }
  __syncthreads();
  f32x4 acc[16];
  #pragma unroll
  for (int i = 0; i < 16; ++i) acc[i] = (f32x4){0.f, 0.f, 0.f, 0.f};
  const u16* wsrc = wb + op * 65536;
  __builtin_amdgcn_s_setprio(1);
  #pragma unroll
  for (int cc = 0; cc < 4; ++cc) {
    short8 afr[2];
    #pragma unroll
    for (int kc = 0; kc < 2; ++kc) {
      int row = wid * 16 + lr;
      int byte = row * 512 + (cc * 64 + kc * 32 + lg * 8) * 2;
      afr[kc] = *(const short8*)(hn_lds + (byte ^ ((row & 7) << 4)));
    }
    #pragma unroll
    for (int cot = 0; cot < 16; ++cot) {
      #pragma unroll
      for (int kc = 0; kc < 2; ++kc) {
        short8 bfr = *(const short8*)(wsrc + (size_t)(cot * 16 + lr) * CDIM +
                                      cc * 64 + kc * 32 + lg * 8);
        acc[cot] = __builtin_amdgcn_mfma_f32_16x16x32_bf16(afr[kc], bfr, acc[cot], 0, 0, 0);
      }
    }
  }
  __builtin_amdgcn_s_setprio(0);
  const float* bias = (op == 0) ? bq : (op == 1) ? bk : bv;
  float bscale = (op == 0) ? QSCALE : 1.0f;
  int nbase = nt * 64 + wid * 16 + lg * 4;
  #pragma unroll
  for (int cot = 0; cot < 16; ++cot) {
    int co = cot * 16 + lr;
    float bv_ = bias[co] * bscale;
    #pragma unroll
    for (int j = 0; j < 4; ++j) {
      float val = acc[cot][j] + bv_;
      int n = nbase + j;
      if (op == 2) {
        vb[((size_t)b * CDIM + co) * NTOK + n] = f2bf(val);
      } else if (op == 1) {
        int tile = n >> 6, row = n & 63;
        int slot = ((co >> 3) + 2 * row) & 31;
        kb[(size_t)b * NTOK * CDIM + (size_t)tile * 16384 + row * 256 +
           slot * 8 + (co & 7)] = f2bf(val);
      } else {
        qb[((size_t)b * NTOK + n) * CDIM + co] = f2bf(val);
      }
    }
  }
}

// ---------------- kernel 5: flash attention ---------------------------------
// 512 threads = 8 waves x 16 q-rows = 128 queries per block.
// Swapped QK^T: lane owns score row for n = q0w + (lane&15).
// K double-buffered in LDS (rotated slot layout, conflict-free, linear stage).
// V fragments direct from global. One barrier per tile.
template <int TPB, bool SPLIT>
__global__ __launch_bounds__(512, 2) void flash_k(const u16* qb, const u16* kb,
                                                  const u16* vb, u16* opart,
                                                  float* ml, u16* ob) {
  int qt = blockIdx.x, b = blockIdx.y, sp = blockIdx.z;
  int tid = threadIdx.x, lane = tid & 63, wid = tid >> 6;
  int lr = lane & 15, lg = lane >> 4;
  __shared__ __align__(16) char k_lds[2][32768];   // [64 row][32 slot][16B]
  __shared__ __align__(16) char p_lds[8][2048];    // per-wave P [16 n][64 m]

  // Q fragments (B operand): lane lr holds Q row (q0 + wid*16 + lr)
  short8 aq[8];
  int nq = qt * 128 + wid * 16 + lr;
  const u16* qsrc = qb + ((size_t)b * NTOK + nq) * CDIM;
  #pragma unroll
  for (int kc = 0; kc < 8; ++kc) aq[kc] = *(const short8*)(qsrc + kc * 32 + lg * 8);

  float mrun = -1e30f, lrun = 0.f;
  f32x4 acc[16];
  #pragma unroll
  for (int i = 0; i < 16; ++i) acc[i] = (f32x4){0.f, 0.f, 0.f, 0.f};

  const u16* vbase = vb + (size_t)b * CDIM * NTOK;
  const char* kbb = (const char*)(kb + (size_t)b * NTOK * CDIM);
  char* pw = p_lds[wid];

  // prologue: stage tile 0 into buf 0 (linear; kb is pre-rotated)
  {
    const char* src = kbb + (size_t)(sp * TPB) * 32768;
    #pragma unroll
    for (int i = 0; i < 4; ++i)
      gload16(src + wid * 4096 + i * 1024 + lane * 16,
              k_lds[0] + wid * 4096 + i * 1024);
  }
  __syncthreads();

  for (int t = 0; t < TPB; ++t) {
    int cur = t & 1;
    int kt = sp * TPB + t;
    if (t + 1 < TPB) {  // prefetch next K tile into other buffer
      const char* src = kbb + (size_t)(kt + 1) * 32768;
      #pragma unroll
      for (int i = 0; i < 4; ++i)
        gload16(src + wid * 4096 + i * 1024 + lane * 16,
                k_lds[cur ^ 1] + wid * 4096 + i * 1024);
    }
    // QK^T (swapped): s[mt] holds S[m = mt*16 + lg*4 + j][n = q0w + lr]
    f32x4 s[4];
    __builtin_amdgcn_s_setprio(1);
    #pragma unroll
    for (int mt = 0; mt < 4; ++mt) {
      f32x4 a = (f32x4){0.f, 0.f, 0.f, 0.f};
      #pragma unroll
      for (int kc = 0; kc < 8; ++kc) {
        int row = mt * 16 + lr;
        int slot = (kc * 4 + lg + 2 * row) & 31;
        short8 kf = *(const short8*)(k_lds[cur] + row * 512 + slot * 16);
        a = __builtin_amdgcn_mfma_f32_16x16x32_bf16(kf, aq[kc], a, 0, 0, 0);
      }
      s[mt] = a;
    }
    __builtin_amdgcn_s_setprio(0);
    // online softmax — fully lane-local except 2+2 shfls
    float pmax = s[0][0];
    #pragma unroll
    for (int mt = 0; mt < 4; ++mt) {
      #pragma unroll
      for (int j = 0; j < 4; ++j) pmax = fmaxf(pmax, s[mt][j]);
    }
    pmax = fmaxf(pmax, __shfl_xor(pmax, 16, 64));
    pmax = fmaxf(pmax, __shfl_xor(pmax, 32, 64));
    float mn = fmaxf(mrun, pmax);
    float r = exp2f(mrun - mn);
    mrun = mn;
    float ls = 0.f;
    #pragma unroll
    for (int mt = 0; mt < 4; ++mt) {
      #pragma unroll
      for (int j = 0; j < 4; ++j) {
        float p = exp2f(s[mt][j] - mn);
        s[mt][j] = p;
        ls += p;
      }
    }
    ls += __shfl_xor(ls, 16, 64);
    ls += __shfl_xor(ls, 32, 64);
    lrun = lrun * r + ls;
    #pragma unroll
    for (int i = 0; i < 16; ++i) {
      acc[i][0] *= r; acc[i][1] *= r; acc[i][2] *= r; acc[i][3] *= r;
    }
    // write P[n=lr][m] as packed bf16 pairs
    #pragma unroll
    for (int mt = 0; mt < 4; ++mt) {
      #pragma unroll
      for (int tp = 0; tp < 2; ++tp) {
        uint32_t pk = (uint32_t)f2bf(s[mt][2 * tp]) |
                      ((uint32_t)f2bf(s[mt][2 * tp + 1]) << 16);
        int byte = lr * 128 + mt * 32 + lg * 8 + tp * 4;
        *(uint32_t*)(pw + (byte ^ ((lr & 7) << 4))) = pk;
      }
    }
    // PV: O^T[c][n] += V^T[c][m] * P[m][n]
    __builtin_amdgcn_s_setprio(1);
    #pragma unroll
    for (int mc = 0; mc < 2; ++mc) {
      int pb = lr * 128 + mc * 64 + lg * 16;
      short8 bfr = *(const short8*)(pw + (pb ^ ((lr & 7) << 4)));
      #pragma unroll
      for (int ct = 0; ct < 16; ++ct) {
        short8 av = *(const short8*)(vbase + (size_t)(ct * 16 + lr) * NTOK +
                                     kt * 64 + mc * 32 + lg * 8);
        acc[ct] = __builtin_amdgcn_mfma_f32_16x16x32_bf16(av, bfr, acc[ct], 0, 0, 0);
      }
    }
    __builtin_amdgcn_s_setprio(0);
    __syncthreads();  // staged loads old by now; all waves done with buffers
  }

  int n = qt * 128 + wid * 16 + lr;
  if (!SPLIT) {
    float linv = 1.0f / lrun;
    #pragma unroll
    for (int ct = 0; ct < 16; ++ct) {
      #pragma unroll
      for (int j = 0; j < 4; ++j) {
        int c = ct * 16 + lg * 4 + j;
        ob[((size_t)b * NTOK + n) * CDIM + c] = f2bf(acc[ct][j] * linv);
      }
    }
  } else {
    // unnormalized partial O^T[c][n] + per-n m,l
    size_t pbase = (size_t)(sp * 2 + b) * CDIM * NTOK;
    #pragma unroll
    for (int ct = 0; ct < 16; ++ct) {
      #pragma unroll
      for (int j = 0; j < 4; ++j) {
        int c = ct * 16 + lg * 4 + j;
        opart[pbase + (size_t)c * NTOK + n] = f2bf(acc[ct][j]);
      }
    }
    if (lg == 0) {
      ml[((size_t)(sp * 2 + b) * 2 + 0) * NTOK + n] = mrun;
      ml[((size_t)(sp * 2 + b) * 2 + 1) * NTOK + n] = lrun;
    }
  }
}

// ---------------- kernel 5b: combine 2 KV-split partials --------------------
__global__ __launch_bounds__(256) void comb_k(const u16* opart, const float* ml,
                                              u16* ob) {
  int nt = blockIdx.x, b = blockIdx.y;
  int tid = threadIdx.x;
  int n = nt * 64 + (tid & 63);
  int cchunk = tid >> 6;   // 4 chunks of 64 channels
  float m0 = ml[((size_t)(0 * 2 + b) * 2 + 0) * NTOK + n];
  float l0 = ml[((size_t)(0 * 2 + b) * 2 + 1) * NTOK + n];
  float m1 = ml[((size_t)(1 * 2 + b) * 2 + 0) * NTOK + n];
  float l1 = ml[((size_t)(1 * 2 + b) * 2 + 1) * NTOK + n];
  float M = fmaxf(m0, m1);
  float w0 = exp2f(m0 - M), w1 = exp2f(m1 - M);
  float inv = 1.f / (w0 * l0 + w1 * l1);
  float a0 = w0 * inv, a1 = w1 * inv;
  const u16* p0 = opart + (size_t)(0 * 2 + b) * CDIM * NTOK;
  const u16* p1 = opart + (size_t)(1 * 2 + b) * CDIM * NTOK;
  u16 buf[64];
  #pragma unroll
  for (int i = 0; i < 64; ++i) {
    int c = cchunk * 64 + i;
    float v = a0 * bf2f(p0[(size_t)c * NTOK + n]) +
              a1 * bf2f(p1[(size_t)c * NTOK + n]);
    buf[i] = f2bf(v);
  }
  #pragma unroll
  for (int i = 0; i < 8; ++i)
    *(short8*)(ob + ((size_t)b * NTOK + n) * CDIM + cchunk * 64 + i * 8) =
        *(const short8*)(buf + i * 8);
}

// ---------------- kernel 6: proj_out + bias + residual ----------------------
__global__ __launch_bounds__(256) void proj_k(const u16* ob, const u16* wb,
    const float* bp, const float* x, float* out) {
  int nt = blockIdx.x, b = blockIdx.y, z = blockIdx.z;
  int tid = threadIdx.x, lane = tid & 63, wid = tid >> 6;
  int lr = lane & 15, lg = lane >> 4;
  __shared__ __align__(16) char o_lds[32768];   // [64 n][256 c] swizzled
  const u16* wpb = wb + 3 * 65536;
  {
    const char* src = (const char*)(ob + ((size_t)b * NTOK + nt * 64) * CDIM);
    #pragma unroll
    for (int i = 0; i < 8; ++i) {
      int off = i * 4096 + wid * 1024 + lane * 16;
      int row = off >> 9;
      gload16(src + (off ^ ((row & 7) << 4)), o_lds + i * 4096 + wid * 1024);
    }
  }
  __syncthreads();
  #pragma unroll
  for (int ct2 = 0; ct2 < 2; ++ct2) {
    int cot = z * 8 + wid * 2 + ct2;
    short8 aw[8];
    #pragma unroll
    for (int kc = 0; kc < 8; ++kc)
      aw[kc] = *(const short8*)(wpb + (size_t)(cot * 16 + lr) * CDIM + kc * 32 + lg * 8);
    #pragma unroll
    for (int ntile = 0; ntile < 4; ++ntile) {
      f32x4 a = (f32x4){0.f, 0.f, 0.f, 0.f};
      #pragma unroll
      for (int kc = 0; kc < 8; ++kc) {
        int row = ntile * 16 + lr;
        int byte = row * 512 + (kc * 32 + lg * 8) * 2;
        short8 bfr = *(const short8*)(o_lds + (byte ^ ((row & 7) << 4)));
        a = __builtin_amdgcn_mfma_f32_16x16x32_bf16(aw[kc], bfr, a, 0, 0, 0);
      }
      int n = nt * 64 + ntile * 16 + lr;
      int f = n / HW; int hw = n - f * HW;
      #pragma unroll
      for (int j = 0; j < 4; ++j) {
        int co = cot * 16 + lg * 4 + j;
        float val = a[j] + bp[co];
        size_t oi = ((size_t)(b * FR + f) * CDIM + co) * HW + hw;
        out[oi] = x[oi] + val;
      }
    }
  }
}

extern "C" void kernel_launch(void* const* d_in, const int* in_sizes, int n_in,
                              void* d_out, int out_size, void* d_ws, size_t ws_size,
                              hipStream_t stream) {
  const float* x    = (const float*)d_in[0];
  const float* gn_w = (const float*)d_in[1];
  const float* gn_b = (const float*)d_in[2];
  const float* wq   = (const float*)d_in[3];
  const float* bq   = (const float*)d_in[4];
  const float* wk   = (const float*)d_in[5];
  const float* bk   = (const float*)d_in[6];
  const float* wv   = (const float*)d_in[7];
  const float* bv   = (const float*)d_in[8];
  const float* wp   = (const float*)d_in[9];
  const float* bp   = (const float*)d_in[10];
  float* out = (float*)d_out;
  char* ws = (char*)d_ws;

  float* stats = (float*)(ws + 0);          // 16 f32
  float* part  = (float*)(ws + 256);        // 512 f32
  u16* wb = (u16*)(ws + 4096);              // 4*256*256
  u16* hn = (u16*)(ws + 528384);            // [2][6912][256]
  u16* qb = (u16*)(ws + 7606272);
  u16* kb = (u16*)(ws + 14684160);          // rotated tile layout
  u16* vb = (u16*)(ws + 21762048);          // [2][256][6912]
  u16* ob = (u16*)(ws + 28839936);
  u16* opart = (u16*)(ws + 35917824);       // [2 sp][2 b][256][6912] bf16
  float* ml  = (float*)(ws + 50073600);     // [2 sp][2 b][2][6912] f32
  const size_t NEED_SPLIT = 50294784;

  cvt_w_k<<<256, 256, 0, stream>>>(wq, wk, wv, wp, wb);
  gn_part_k<<<256, 256, 0, stream>>>(x, part);
  gn_fin_k<<<1, 64, 0, stream>>>(part, stats);
  gn_apply_k<<<dim3(108, 4, 2), 256, 0, stream>>>(x, gn_w, gn_b, stats, hn);
  qkv_k<<<dim3(108, 6), 256, 0, stream>>>(hn, wb, bq, bk, bv, qb, kb, vb);
  if (ws_size >= NEED_SPLIT) {
    flash_k<54, true><<<dim3(54, 2, 2), 512, 0, stream>>>(qb, kb, vb, opart, ml, ob);
    comb_k<<<dim3(108, 2), 256, 0, stream>>>(opart, ml, ob);
  } else {
    flash_k<108, false><<<dim3(54, 2, 1), 512, 0, stream>>>(qb, kb, vb, opart, ml, ob);
  }
  proj_k<<<dim3(108, 2, 2), 256, 0, stream>>>(ob, wb, bp, x, out);
}

// Round 4
// 267.844 us; speedup vs baseline: 5.2424x; 2.2004x over previous
//
#include <hip/hip_runtime.h>
#include <stdint.h>

#define CDIM 256
#define HW 2304
#define FR 3
#define NBATCH 2
#define NTOK 6912
#define EPSV 1e-6f
#define LOG2E 1.44269504088896f
#define QSCALE (0.0625f * 1.44269504088896f)

typedef __attribute__((ext_vector_type(8))) short short8;
typedef __attribute__((ext_vector_type(4))) float f32x4;
typedef unsigned short u16;

__device__ inline u16 f2bf(float f) {
  union { float f; uint32_t u; } v; v.f = f;
  uint32_t r = v.u + 0x7FFFu + ((v.u >> 16) & 1u);
  return (u16)(r >> 16);
}
__device__ inline float bf2f(u16 h) {
  union { uint32_t u; float f; } v; v.u = ((uint32_t)h) << 16; return v.f;
}
// async global->LDS, 16B per lane; dest = wave-uniform base + lane*16
__device__ inline void gload16(const void* g, void* l) {
  __builtin_amdgcn_global_load_lds(
      (const __attribute__((address_space(1))) void*)g,
      (__attribute__((address_space(3))) void*)l, 16, 0, 0);
}

// ---------------- kernel 1: weights -> bf16 (scale+LOG2E folded into wq) ----
__global__ void cvt_w_k(const float* wq, const float* wk, const float* wv,
                        const float* wp, u16* wb) {
  int idx = blockIdx.x * 256 + threadIdx.x;
  wb[0 * 65536 + idx] = f2bf(wq[idx] * QSCALE);
  wb[1 * 65536 + idx] = f2bf(wk[idx]);
  wb[2 * 65536 + idx] = f2bf(wv[idx]);
  wb[3 * 65536 + idx] = f2bf(wp[idx]);
}

// ---------------- kernel 2a: GroupNorm partial sums (256 blocks) ------------
__global__ void gn_part_k(const float* x, float* part) {
  int bg = blockIdx.x >> 5, sl = blockIdx.x & 31;
  int b = bg >> 2, g = bg & 3;
  int tid = threadIdx.x;
  float s1 = 0.f, s2 = 0.f;
  for (int i = tid; i < 2 * NTOK; i += 256) {
    int cl = sl * 2 + (i / NTOK); int rem = i % NTOK;
    int f = rem / HW; int hw = rem - f * HW;
    float v = x[((size_t)(f * NBATCH + b) * CDIM + g * 64 + cl) * HW + hw];
    s1 += v; s2 += v * v;
  }
  #pragma unroll
  for (int m = 32; m >= 1; m >>= 1) {
    s1 += __shfl_xor(s1, m, 64);
    s2 += __shfl_xor(s2, m, 64);
  }
  __shared__ float r1[4], r2[4];
  int wid = tid >> 6;
  if ((tid & 63) == 0) { r1[wid] = s1; r2[wid] = s2; }
  __syncthreads();
  if (tid == 0) {
    part[blockIdx.x * 2 + 0] = r1[0] + r1[1] + r1[2] + r1[3];
    part[blockIdx.x * 2 + 1] = r2[0] + r2[1] + r2[2] + r2[3];
  }
}

// ---------------- kernel 2b: finalize stats ---------------------------------
__global__ void gn_fin_k(const float* part, float* stats) {
  int tid = threadIdx.x;
  if (tid < 8) {
    float s1 = 0.f, s2 = 0.f;
    for (int s = 0; s < 32; ++s) {
      s1 += part[(tid * 32 + s) * 2 + 0];
      s2 += part[(tid * 32 + s) * 2 + 1];
    }
    float inv = 1.f / (64.f * NTOK);
    float mu = s1 * inv;
    float var = s2 * inv - mu * mu;
    stats[tid * 2 + 0] = mu;
    stats[tid * 2 + 1] = rsqrtf(var + EPSV);
  }
}

// ---------------- kernel 3: normalize + transpose -> hn[b][n][c] bf16 -------
__global__ void gn_apply_k(const float* x, const float* gn_w, const float* gn_b,
                           const float* stats, u16* hn) {
  int nt = blockIdx.x, ct = blockIdx.y, b = blockIdx.z;
  int tid = threadIdx.x;
  __shared__ float tile[64][65];
  int n0 = nt * 64; int f = n0 / HW; int hw0 = n0 - f * HW;
  float mu = stats[(b * 4 + ct) * 2 + 0];
  float rs = stats[(b * 4 + ct) * 2 + 1];
  #pragma unroll
  for (int i = 0; i < 16; ++i) {
    int lin = i * 256 + tid;
    int cr = lin >> 6, nc = lin & 63;
    int c = ct * 64 + cr;
    float v = x[((size_t)(f * NBATCH + b) * CDIM + c) * HW + hw0 + nc];
    tile[cr][nc] = (v - mu) * rs * gn_w[c] + gn_b[c];
  }
  __syncthreads();
  #pragma unroll
  for (int i = 0; i < 16; ++i) {
    int lin = i * 256 + tid;
    int nr = lin >> 6, cc = lin & 63;
    hn[((size_t)b * NTOK + n0 + nr) * CDIM + ct * 64 + cc] = f2bf(tile[cc][nr]);
  }
}

// ---------------- kernel 4: QKV GEMM ----------------------------------------
// D[n][co] = sum_c hn[n][c] * w[co][c]
// q -> [b][n][co] (scaled, log2-domain)
// k -> rotated tile layout: kb[b][tile][row][slot32][8], slot32=((co>>3)+2*row)&31
// v -> rotated tile layout: vb[b][tile][co][slot8][8],  slot8 =((m>>3)+co)&7
__global__ __launch_bounds__(256) void qkv_k(const u16* hn, const u16* wb,
    const float* bq, const float* bk, const float* bv,
    u16* qb, u16* kb, u16* vb) {
  int nt = blockIdx.x;
  int op = blockIdx.y >> 1, b = blockIdx.y & 1;
  int tid = threadIdx.x, lane = tid & 63, wid = tid >> 6;
  int lr = lane & 15, lg = lane >> 4;
  __shared__ __align__(16) char hn_lds[32768];   // [64 n][256 c] swizzled
  {
    const char* src = (const char*)(hn + ((size_t)b * NTOK + nt * 64) * CDIM);
    #pragma unroll
    for (int i = 0; i < 8; ++i) {
      int off = i * 4096 + wid * 1024 + lane * 16;
      int row = off >> 9;
      gload16(src + (off ^ ((row & 7) << 4)), hn_lds + i * 4096 + wid * 1024);
    }
  }
  __syncthreads();
  f32x4 acc[16];
  #pragma unroll
  for (int i = 0; i < 16; ++i) acc[i] = (f32x4){0.f, 0.f, 0.f, 0.f};
  const u16* wsrc = wb + op * 65536;
  __builtin_amdgcn_s_setprio(1);
  #pragma unroll
  for (int cc = 0; cc < 4; ++cc) {
    short8 afr[2];
    #pragma unroll
    for (int kc = 0; kc < 2; ++kc) {
      int row = wid * 16 + lr;
      int byte = row * 512 + (cc * 64 + kc * 32 + lg * 8) * 2;
      afr[kc] = *(const short8*)(hn_lds + (byte ^ ((row & 7) << 4)));
    }
    #pragma unroll
    for (int cot = 0; cot < 16; ++cot) {
      #pragma unroll
      for (int kc = 0; kc < 2; ++kc) {
        short8 bfr = *(const short8*)(wsrc + (size_t)(cot * 16 + lr) * CDIM +
                                      cc * 64 + kc * 32 + lg * 8);
        acc[cot] = __builtin_amdgcn_mfma_f32_16x16x32_bf16(afr[kc], bfr, acc[cot], 0, 0, 0);
      }
    }
  }
  __builtin_amdgcn_s_setprio(0);
  const float* bias = (op == 0) ? bq : (op == 1) ? bk : bv;
  float bscale = (op == 0) ? QSCALE : 1.0f;
  int nbase = nt * 64 + wid * 16 + lg * 4;
  #pragma unroll
  for (int cot = 0; cot < 16; ++cot) {
    int co = cot * 16 + lr;
    float bv_ = bias[co] * bscale;
    #pragma unroll
    for (int j = 0; j < 4; ++j) {
      float val = acc[cot][j] + bv_;
      int n = nbase + j;
      if (op == 2) {
        int tile = n >> 6, m = n & 63;
        int slot = ((m >> 3) + co) & 7;
        vb[(size_t)b * NTOK * CDIM + (size_t)tile * 16384 + co * 64 +
           slot * 8 + (m & 7)] = f2bf(val);
      } else if (op == 1) {
        int tile = n >> 6, row = n & 63;
        int slot = ((co >> 3) + 2 * row) & 31;
        kb[(size_t)b * NTOK * CDIM + (size_t)tile * 16384 + row * 256 +
           slot * 8 + (co & 7)] = f2bf(val);
      } else {
        qb[((size_t)b * NTOK + n) * CDIM + co] = f2bf(val);
      }
    }
  }
}

// ---------------- kernel 5: flash attention ---------------------------------
// 512 threads = 8 waves x 16 q-rows = 128 queries per block.
// Swapped QK^T: lane owns score row for n = q0w + (lane&15).
// K and V double-buffered in LDS (rotated layouts, bank-balanced, linear
// global_load_lds staging). One barrier per tile. Defer-max rescale (THR=6).
template <int TPB, bool SPLIT>
__global__ __launch_bounds__(512, 2) void flash_k(const u16* qb, const u16* kb,
                                                  const u16* vb, u16* opart,
                                                  float* ml, u16* ob) {
  int qt = blockIdx.x, b = blockIdx.y, sp = blockIdx.z;
  int tid = threadIdx.x, lane = tid & 63, wid = tid >> 6;
  int lr = lane & 15, lg = lane >> 4;
  __shared__ __align__(16) char k_lds[2][32768];   // [64 row][32 slot][16B]
  __shared__ __align__(16) char v_lds[2][32768];   // [256 co][8 slot][16B]
  __shared__ __align__(16) char p_lds[8][2048];    // per-wave P [16 n][64 m]

  // Q fragments (B operand): lane lr holds Q row (q0 + wid*16 + lr)
  short8 aq[8];
  int nq = qt * 128 + wid * 16 + lr;
  const u16* qsrc = qb + ((size_t)b * NTOK + nq) * CDIM;
  #pragma unroll
  for (int kc = 0; kc < 8; ++kc) aq[kc] = *(const short8*)(qsrc + kc * 32 + lg * 8);

  float mrun = -1e30f, lrun = 0.f;
  f32x4 acc[16];
  #pragma unroll
  for (int i = 0; i < 16; ++i) acc[i] = (f32x4){0.f, 0.f, 0.f, 0.f};

  const char* kbb = (const char*)(kb + (size_t)b * NTOK * CDIM);
  const char* vbb = (const char*)(vb + (size_t)b * NTOK * CDIM);
  char* pw = p_lds[wid];

  // prologue: stage tile 0 into buf 0 (linear; kb/vb are pre-rotated)
  {
    const char* ks = kbb + (size_t)(sp * TPB) * 32768;
    const char* vs = vbb + (size_t)(sp * TPB) * 32768;
    #pragma unroll
    for (int i = 0; i < 4; ++i) {
      gload16(ks + wid * 4096 + i * 1024 + lane * 16,
              k_lds[0] + wid * 4096 + i * 1024);
      gload16(vs + wid * 4096 + i * 1024 + lane * 16,
              v_lds[0] + wid * 4096 + i * 1024);
    }
  }
  __syncthreads();

  for (int t = 0; t < TPB; ++t) {
    int cur = t & 1;
    int kt = sp * TPB + t;
    if (t + 1 < TPB) {  // prefetch next K+V tiles into other buffers
      const char* ks = kbb + (size_t)(kt + 1) * 32768;
      const char* vs = vbb + (size_t)(kt + 1) * 32768;
      #pragma unroll
      for (int i = 0; i < 4; ++i) {
        gload16(ks + wid * 4096 + i * 1024 + lane * 16,
                k_lds[cur ^ 1] + wid * 4096 + i * 1024);
        gload16(vs + wid * 4096 + i * 1024 + lane * 16,
                v_lds[cur ^ 1] + wid * 4096 + i * 1024);
      }
    }
    // QK^T (swapped): s[mt] holds S[m = mt*16 + lg*4 + j][n = q0w + lr]
    f32x4 s[4];
    __builtin_amdgcn_s_setprio(1);
    #pragma unroll
    for (int mt = 0; mt < 4; ++mt) {
      f32x4 a = (f32x4){0.f, 0.f, 0.f, 0.f};
      #pragma unroll
      for (int kc = 0; kc < 8; ++kc) {
        int row = mt * 16 + lr;
        int slot = (kc * 4 + lg + 2 * row) & 31;
        short8 kf = *(const short8*)(k_lds[cur] + row * 512 + slot * 16);
        a = __builtin_amdgcn_mfma_f32_16x16x32_bf16(kf, aq[kc], a, 0, 0, 0);
      }
      s[mt] = a;
    }
    __builtin_amdgcn_s_setprio(0);
    // online softmax — lane-local, log2 domain; max via tree + 2 shfls
    float m0 = fmaxf(fmaxf(s[0][0], s[0][1]), fmaxf(s[0][2], s[0][3]));
    float m1 = fmaxf(fmaxf(s[1][0], s[1][1]), fmaxf(s[1][2], s[1][3]));
    float m2 = fmaxf(fmaxf(s[2][0], s[2][1]), fmaxf(s[2][2], s[2][3]));
    float m3 = fmaxf(fmaxf(s[3][0], s[3][1]), fmaxf(s[3][2], s[3][3]));
    float pmax = fmaxf(fmaxf(m0, m1), fmaxf(m2, m3));
    pmax = fmaxf(pmax, __shfl_xor(pmax, 16, 64));
    pmax = fmaxf(pmax, __shfl_xor(pmax, 32, 64));
    float mn = mrun;
    if (__any(pmax > mrun + 6.0f)) {  // defer-max: rescale only on real growth
      mn = fmaxf(mrun, pmax);
      float r = exp2f(mrun - mn);
      mrun = mn;
      lrun *= r;
      #pragma unroll
      for (int i = 0; i < 16; ++i) {
        acc[i][0] *= r; acc[i][1] *= r; acc[i][2] *= r; acc[i][3] *= r;
      }
    }
    float ls = 0.f;
    #pragma unroll
    for (int mt = 0; mt < 4; ++mt) {
      #pragma unroll
      for (int j = 0; j < 4; ++j) {
        float p = exp2f(s[mt][j] - mn);
        s[mt][j] = p;
        ls += p;
      }
    }
    ls += __shfl_xor(ls, 16, 64);
    ls += __shfl_xor(ls, 32, 64);
    lrun += ls;
    // write P[n=lr][m] as packed bf16 pairs
    #pragma unroll
    for (int mt = 0; mt < 4; ++mt) {
      #pragma unroll
      for (int tp = 0; tp < 2; ++tp) {
        uint32_t pk = (uint32_t)f2bf(s[mt][2 * tp]) |
                      ((uint32_t)f2bf(s[mt][2 * tp + 1]) << 16);
        int byte = lr * 128 + mt * 32 + lg * 8 + tp * 4;
        *(uint32_t*)(pw + (byte ^ ((lr & 7) << 4))) = pk;
      }
    }
    // PV: O^T[c][n] += V^T[c][m] * P[m][n]; V from LDS (rotated slots)
    __builtin_amdgcn_s_setprio(1);
    #pragma unroll
    for (int mc = 0; mc < 2; ++mc) {
      int pb = lr * 128 + mc * 64 + lg * 16;
      short8 bfr = *(const short8*)(pw + (pb ^ ((lr & 7) << 4)));
      #pragma unroll
      for (int ct = 0; ct < 16; ++ct) {
        int row = ct * 16 + lr;
        int slot = (mc * 4 + lg + row) & 7;
        short8 av = *(const short8*)(v_lds[cur] + row * 128 + slot * 16);
        acc[ct] = __builtin_amdgcn_mfma_f32_16x16x32_bf16(av, bfr, acc[ct], 0, 0, 0);
      }
    }
    __builtin_amdgcn_s_setprio(0);
    __syncthreads();  // staged loads old by now; all waves done with buffers
  }

  int n = qt * 128 + wid * 16 + lr;
  if (!SPLIT) {
    float linv = 1.0f / lrun;
    #pragma unroll
    for (int ct = 0; ct < 16; ++ct) {
      #pragma unroll
      for (int j = 0; j < 4; ++j) {
        int c = ct * 16 + lg * 4 + j;
        ob[((size_t)b * NTOK + n) * CDIM + c] = f2bf(acc[ct][j] * linv);
      }
    }
  } else {
    // unnormalized partial O^T[c][n] + per-n m,l
    size_t pbase = (size_t)(sp * 2 + b) * CDIM * NTOK;
    #pragma unroll
    for (int ct = 0; ct < 16; ++ct) {
      #pragma unroll
      for (int j = 0; j < 4; ++j) {
        int c = ct * 16 + lg * 4 + j;
        opart[pbase + (size_t)c * NTOK + n] = f2bf(acc[ct][j]);
      }
    }
    if (lg == 0) {
      ml[((size_t)(sp * 2 + b) * 2 + 0) * NTOK + n] = mrun;
      ml[((size_t)(sp * 2 + b) * 2 + 1) * NTOK + n] = lrun;
    }
  }
}

// ---------------- kernel 5b: combine 2 KV-split partials --------------------
__global__ __launch_bounds__(256) void comb_k(const u16* opart, const float* ml,
                                              u16* ob) {
  int nt = blockIdx.x, b = blockIdx.y;
  int tid = threadIdx.x;
  int n = nt * 64 + (tid & 63);
  int cchunk = tid >> 6;   // 4 chunks of 64 channels
  float m0 = ml[((size_t)(0 * 2 + b) * 2 + 0) * NTOK + n];
  float l0 = ml[((size_t)(0 * 2 + b) * 2 + 1) * NTOK + n];
  float m1 = ml[((size_t)(1 * 2 + b) * 2 + 0) * NTOK + n];
  float l1 = ml[((size_t)(1 * 2 + b) * 2 + 1) * NTOK + n];
  float M = fmaxf(m0, m1);
  float w0 = exp2f(m0 - M), w1 = exp2f(m1 - M);
  float inv = 1.f / (w0 * l0 + w1 * l1);
  float a0 = w0 * inv, a1 = w1 * inv;
  const u16* p0 = opart + (size_t)(0 * 2 + b) * CDIM * NTOK;
  const u16* p1 = opart + (size_t)(1 * 2 + b) * CDIM * NTOK;
  u16 buf[64];
  #pragma unroll
  for (int i = 0; i < 64; ++i) {
    int c = cchunk * 64 + i;
    float v = a0 * bf2f(p0[(size_t)c * NTOK + n]) +
              a1 * bf2f(p1[(size_t)c * NTOK + n]);
    buf[i] = f2bf(v);
  }
  #pragma unroll
  for (int i = 0; i < 8; ++i)
    *(short8*)(ob + ((size_t)b * NTOK + n) * CDIM + cchunk * 64 + i * 8) =
        *(const short8*)(buf + i * 8);
}

// ---------------- kernel 6: proj_out + bias + residual ----------------------
__global__ __launch_bounds__(256) void proj_k(const u16* ob, const u16* wb,
    const float* bp, const float* x, float* out) {
  int nt = blockIdx.x, b = blockIdx.y, z = blockIdx.z;
  int tid = threadIdx.x, lane = tid & 63, wid = tid >> 6;
  int lr = lane & 15, lg = lane >> 4;
  __shared__ __align__(16) char o_lds[32768];   // [64 n][256 c] swizzled
  const u16* wpb = wb + 3 * 65536;
  {
    const char* src = (const char*)(ob + ((size_t)b * NTOK + nt * 64) * CDIM);
    #pragma unroll
    for (int i = 0; i < 8; ++i) {
      int off = i * 4096 + wid * 1024 + lane * 16;
      int row = off >> 9;
      gload16(src + (off ^ ((row & 7) << 4)), o_lds + i * 4096 + wid * 1024);
    }
  }
  __syncthreads();
  #pragma unroll
  for (int ct2 = 0; ct2 < 2; ++ct2) {
    int cot = z * 8 + wid * 2 + ct2;
    short8 aw[8];
    #pragma unroll
    for (int kc = 0; kc < 8; ++kc)
      aw[kc] = *(const short8*)(wpb + (size_t)(cot * 16 + lr) * CDIM + kc * 32 + lg * 8);
    #pragma unroll
    for (int ntile = 0; ntile < 4; ++ntile) {
      f32x4 a = (f32x4){0.f, 0.f, 0.f, 0.f};
      #pragma unroll
      for (int kc = 0; kc < 8; ++kc) {
        int row = ntile * 16 + lr;
        int byte = row * 512 + (kc * 32 + lg * 8) * 2;
        short8 bfr = *(const short8*)(o_lds + (byte ^ ((row & 7) << 4)));
        a = __builtin_amdgcn_mfma_f32_16x16x32_bf16(aw[kc], bfr, a, 0, 0, 0);
      }
      int n = nt * 64 + ntile * 16 + lr;
      int f = n / HW; int hw = n - f * HW;
      #pragma unroll
      for (int j = 0; j < 4; ++j) {
        int co = cot * 16 + lg * 4 + j;
        float val = a[j] + bp[co];
        size_t oi = ((size_t)(b * FR + f) * CDIM + co) * HW + hw;
        out[oi] = x[oi] + val;
      }
    }
  }
}

extern "C" void kernel_launch(void* const* d_in, const int* in_sizes, int n_in,
                              void* d_out, int out_size, void* d_ws, size_t ws_size,
                              hipStream_t stream) {
  const float* x    = (const float*)d_in[0];
  const float* gn_w = (const float*)d_in[1];
  const float* gn_b = (const float*)d_in[2];
  const float* wq   = (const float*)d_in[3];
  const float* bq   = (const float*)d_in[4];
  const float* wk   = (const float*)d_in[5];
  const float* bk   = (const float*)d_in[6];
  const float* wv   = (const float*)d_in[7];
  const float* bv   = (const float*)d_in[8];
  const float* wp   = (const float*)d_in[9];
  const float* bp   = (const float*)d_in[10];
  float* out = (float*)d_out;
  char* ws = (char*)d_ws;

  float* stats = (float*)(ws + 0);          // 16 f32
  float* part  = (float*)(ws + 256);        // 512 f32
  u16* wb = (u16*)(ws + 4096);              // 4*256*256
  u16* hn = (u16*)(ws + 528384);            // [2][6912][256]
  u16* qb = (u16*)(ws + 7606272);
  u16* kb = (u16*)(ws + 14684160);          // rotated tile layout
  u16* vb = (u16*)(ws + 21762048);          // rotated tile layout
  u16* ob = (u16*)(ws + 28839936);
  u16* opart = (u16*)(ws + 35917824);       // [2 sp][2 b][256][6912] bf16
  float* ml  = (float*)(ws + 50073600);     // [2 sp][2 b][2][6912] f32
  const size_t NEED_SPLIT = 50294784;

  cvt_w_k<<<256, 256, 0, stream>>>(wq, wk, wv, wp, wb);
  gn_part_k<<<256, 256, 0, stream>>>(x, part);
  gn_fin_k<<<1, 64, 0, stream>>>(part, stats);
  gn_apply_k<<<dim3(108, 4, 2), 256, 0, stream>>>(x, gn_w, gn_b, stats, hn);
  qkv_k<<<dim3(108, 6), 256, 0, stream>>>(hn, wb, bq, bk, bv, qb, kb, vb);
  if (ws_size >= NEED_SPLIT) {
    flash_k<54, true><<<dim3(54, 2, 2), 512, 0, stream>>>(qb, kb, vb, opart, ml, ob);
    comb_k<<<dim3(108, 2), 256, 0, stream>>>(opart, ml, ob);
  } else {
    flash_k<108, false><<<dim3(54, 2, 1), 512, 0, stream>>>(qb, kb, vb, opart, ml, ob);
  }
  proj_k<<<dim3(108, 2, 2), 256, 0, stream>>>(ob, wb, bp, x, out);
}